// Round 2
// baseline (682.438 us; speedup 1.0000x reference)
//
#include <hip/hip_runtime.h>
#include <hip/hip_bf16.h>

// Scatter-mean pooling: x (N=1048576, D=128) fp32, batch sorted int32 (N,),
// out (num_graphs=4096, D=128) fp32.
//
// R4 change vs R3 (648.5 us) -- resubmitted unchanged in R5 after a
// GPUAcquisitionTimeout (no measurement happened):
//  - Loads switched from __builtin_nontemporal_load to PLAIN cached loads.
//    The 6.29 TB/s streaming ceiling (float4 copy ubench) was measured with
//    plain loads; the nt flag is the only instruction-level difference
//    between pool_mean's access pattern and that reference. Testing the
//    hypothesis that nt caps streaming BW (~1.8 TB/s observed budget).
//  - Accumulator split into two independent chains (acc0/acc1) so the
//    8-deep load pipeline drains through two parallel dependency chains
//    instead of one serial staircase.
//  Structure otherwise identical:
//  Kernel A (find_starts): thread i compares batch[i] vs batch[i-1]; writes
//    run starts; covers s=0, empty segments, and the tail.
//  Kernel B (pool_mean): one block per segment; bounds via two broadcast
//    loads of starts[]; streams ~256 rows with an 8-deep float4 pipeline;
//    LDS-reduces 8 row-lanes; scales by 1/max(cnt,1); nt store of 512 B.

#define D       128
#define D4      32      // float4 per row
#define THREADS 256
#define RIF     8       // rows in flight per pass = THREADS / D4
#define UNROLL  8

typedef float v4f __attribute__((ext_vector_type(4)));

__global__ __launch_bounds__(256)
void find_starts_kernel(const int* __restrict__ batch,
                        int* __restrict__ starts,
                        int n_rows, int num_graphs) {
    int i = blockIdx.x * blockDim.x + threadIdx.x;
    if (i >= n_rows) return;
    int b    = batch[i];
    int prev = (i == 0) ? -1 : batch[i - 1];
    for (int s = prev + 1; s <= b; ++s) starts[s] = i;       // run starts
    if (i == n_rows - 1) {
        for (int s = b + 1; s <= num_graphs; ++s) starts[s] = n_rows; // tail
    }
}

__global__ __launch_bounds__(THREADS)
void pool_mean_kernel(const v4f* __restrict__ x,
                      const int* __restrict__ starts,
                      float* __restrict__ out) {
    const int s = blockIdx.x;

    // Two same-address broadcast loads (L2-hot 16 KiB array) -- no chain.
    const int lo  = starts[s];
    const int hi  = starts[s + 1];
    const int cnt = hi - lo;
    const float inv = 1.0f / (float)(cnt > 1 ? cnt : 1);

    const int col = threadIdx.x & (D4 - 1);   // float4 column 0..31
    const int rl  = threadIdx.x >> 5;         // row lane 0..7

    v4f acc0 = (v4f){0.f, 0.f, 0.f, 0.f};
    v4f acc1 = (v4f){0.f, 0.f, 0.f, 0.f};

    // 8-deep software pipeline over this thread's rows (lo+rl, step 8).
    // Plain (cached) loads -- matches the 6.29 TB/s copy-ubench pattern.
    int i = lo + rl;
    const v4f* p = x + (size_t)i * D4 + col;
    for (; i + (UNROLL - 1) * RIF < hi; i += UNROLL * RIF) {
        v4f v0 = p[0 * RIF * D4];
        v4f v1 = p[1 * RIF * D4];
        v4f v2 = p[2 * RIF * D4];
        v4f v3 = p[3 * RIF * D4];
        v4f v4 = p[4 * RIF * D4];
        v4f v5 = p[5 * RIF * D4];
        v4f v6 = p[6 * RIF * D4];
        v4f v7 = p[7 * RIF * D4];
        acc0 += v0; acc1 += v1; acc0 += v2; acc1 += v3;
        acc0 += v4; acc1 += v5; acc0 += v6; acc1 += v7;
        p += UNROLL * RIF * D4;
    }
    for (; i < hi; i += RIF) {
        acc0 += *p;
        p += RIF * D4;
    }
    acc0 += acc1;

    // Reduce 8 row-lanes -> 1 via LDS.
    __shared__ v4f partials[RIF][D4];
    partials[rl][col] = acc0;
    __syncthreads();

    if (threadIdx.x < D4) {
        v4f t = partials[0][col];
        #pragma unroll
        for (int r = 1; r < RIF; ++r) t += partials[r][col];
        t *= inv;
        v4f* o = (v4f*)out + (size_t)s * D4 + col;
        __builtin_nontemporal_store(t, o);
    }
}

extern "C" void kernel_launch(void* const* d_in, const int* in_sizes, int n_in,
                              void* d_out, int out_size, void* d_ws, size_t ws_size,
                              hipStream_t stream) {
    const v4f* x      = (const v4f*)d_in[0];
    const int* batch  = (const int*)d_in[1];
    float* out        = (float*)d_out;
    int* starts       = (int*)d_ws;           // (num_graphs+1) ints

    const int n_rows     = in_sizes[0] / D;   // 1048576
    const int num_graphs = out_size / D;      // 4096

    find_starts_kernel<<<(n_rows + 255) / 256, 256, 0, stream>>>(
        batch, starts, n_rows, num_graphs);
    pool_mean_kernel<<<num_graphs, THREADS, 0, stream>>>(x, starts, out);
}